// Round 10
// baseline (133.492 us; speedup 1.0000x reference)
//
#include <hip/hip_runtime.h>
#include <hip/hip_bf16.h>

// Shapes (fixed): B=2, S=2048, E=1024, H=16, D=64
// d_out: out[4194304] fp32 | k[4194304] fp32 [B,H,S,D] | v[4194304] fp32 [B,H,S,D]
// ws: x_bf | wT1 | wT2 | q_bf | k_bf | vT_bf ; o_bf aliases x_bf.

typedef __attribute__((ext_vector_type(4))) float f32x4;
typedef __attribute__((ext_vector_type(8))) short s16x8;
typedef __attribute__((ext_vector_type(4))) short s16x4;

__device__ __forceinline__ short f2bf(float f) {
    union { float f; unsigned u; } x{f};
    unsigned r = x.u + 0x7fff + ((x.u >> 16) & 1);
    return (short)(r >> 16);
}

__device__ __forceinline__ void gload_lds16(const void* g, void* l) {
    __builtin_amdgcn_global_load_lds(
        (const __attribute__((address_space(1))) void*)g,
        (__attribute__((address_space(3))) void*)l, 16, 0, 0);
}

// ---------------- pre-pass kernels ----------------

__global__ __launch_bounds__(256) void convert_f32_bf16(const float* __restrict__ in,
                                                        short* __restrict__ out, int n) {
    int i = (blockIdx.x * 256 + threadIdx.x) * 8;
    if (i + 7 < n) {
        f32x4 a = *(const f32x4*)&in[i];
        f32x4 b = *(const f32x4*)&in[i + 4];
        s16x8 o;
        #pragma unroll
        for (int j = 0; j < 4; ++j) o[j] = f2bf(a[j]);
        #pragma unroll
        for (int j = 0; j < 4; ++j) o[j + 4] = f2bf(b[j]);
        *(s16x8*)&out[i] = o;
    }
}

// in: [K][N] fp32 row-major -> out: [N][K] bf16 row-major
__global__ __launch_bounds__(256) void transpose_conv(const float* __restrict__ in,
                                                      short* __restrict__ out, int K, int N) {
    __shared__ float tile[32][33];
    int tx = threadIdx.x, ty = threadIdx.y;  // 32 x 8
    int n0 = blockIdx.x * 32, k0 = blockIdx.y * 32;
    #pragma unroll
    for (int r = 0; r < 4; ++r)
        tile[ty + r * 8][tx] = in[(long)(k0 + ty + r * 8) * N + n0 + tx];
    __syncthreads();
    #pragma unroll
    for (int r = 0; r < 4; ++r)
        out[(long)(n0 + ty + r * 8) * K + k0 + tx] = f2bf(tile[tx][ty + r * 8]);
}

// vout fp32 [32][2048][64] (in d_out) -> vT_bf [32][64][2048] bf16, coalesced both sides
__global__ __launch_bounds__(256) void transpose_v(const float* __restrict__ vin,
                                                   short* __restrict__ vT) {
    __shared__ float tile[32][33];
    const int bh = blockIdx.z;
    const int s0 = blockIdx.x * 32, d0 = blockIdx.y * 32;
    const int tx = threadIdx.x, ty = threadIdx.y;  // 32 x 8
    const float* src = vin + (long)bh * 2048 * 64;
    short* dst = vT + (long)bh * 64 * 2048;
    #pragma unroll
    for (int r = 0; r < 4; ++r)
        tile[ty + r * 8][tx] = src[(long)(s0 + ty + r * 8) * 64 + d0 + tx];
    __syncthreads();
    #pragma unroll
    for (int r = 0; r < 4; ++r)
        dst[(long)(d0 + ty + r * 8) * 2048 + s0 + tx] = f2bf(tile[tx][ty + r * 8]);
}

// ---------------- GEMM (m97-style: 128x128 tile, BK=32, global_load_lds) ----------------
// A: [M][K] bf16, Bt: [N][K] bf16.  MODE 1: qkv epilogue. MODE 2: plain bias epilogue.

template <int MODE>
__global__ __launch_bounds__(256) void gemm_bf16(
    const short* __restrict__ A, const short* __restrict__ Bt,
    const float* __restrict__ bias, int M, int N, int K,
    float* __restrict__ outf,
    short* __restrict__ qbf, short* __restrict__ kbf,
    float* __restrict__ kout, float* __restrict__ vout) {
    __shared__ __align__(16) short As[128 * 32];
    __shared__ __align__(16) short Bs[128 * 32];
    const int tid = threadIdx.x;
    const int l = tid & 63, w = tid >> 6;
    const int lr = l >> 4, lc = l & 15;
    const int wm = w >> 1, wn = w & 1;
    const int m0 = blockIdx.y * 128, n0 = blockIdx.x * 128;

    f32x4 acc[4][4] = {};
    const int c0 = tid, c1 = tid + 256;  // 16B chunks; chunk c -> row c>>2, seg c&3

    for (int kb = 0; kb < K; kb += 32) {
        __syncthreads();
        gload_lds16(A + (long)(m0 + (c0 >> 2)) * K + kb + (c0 & 3) * 8, As + c0 * 8);
        gload_lds16(A + (long)(m0 + (c1 >> 2)) * K + kb + (c1 & 3) * 8, As + c1 * 8);
        gload_lds16(Bt + (long)(n0 + (c0 >> 2)) * K + kb + (c0 & 3) * 8, Bs + c0 * 8);
        gload_lds16(Bt + (long)(n0 + (c1 >> 2)) * K + kb + (c1 & 3) * 8, Bs + c1 * 8);
        __syncthreads();
        s16x8 af[4], bfr[4];
        #pragma unroll
        for (int mi = 0; mi < 4; ++mi)
            af[mi] = *(const s16x8*)&As[(wm * 64 + mi * 16 + lc) * 32 + lr * 8];
        #pragma unroll
        for (int ni = 0; ni < 4; ++ni)
            bfr[ni] = *(const s16x8*)&Bs[(wn * 64 + ni * 16 + lc) * 32 + lr * 8];
        #pragma unroll
        for (int mi = 0; mi < 4; ++mi)
            #pragma unroll
            for (int ni = 0; ni < 4; ++ni)
                acc[mi][ni] = __builtin_amdgcn_mfma_f32_16x16x32_bf16(
                    af[mi], bfr[ni], acc[mi][ni], 0, 0, 0);
    }

    #pragma unroll
    for (int mi = 0; mi < 4; ++mi) {
        #pragma unroll
        for (int ni = 0; ni < 4; ++ni) {
            int col = n0 + wn * 64 + ni * 16 + lc;
            float bv = bias[col];
            if (MODE == 1) {
                int sec = col >> 10, rem = col & 1023;
                int h = rem >> 6, d = rem & 63;
                int row0 = m0 + wm * 64 + mi * 16 + lr * 4;
                int b = row0 >> 11, s0 = row0 & 2047;
                long idxSD = ((long)((b << 4) + h) * 2048 + s0) * 64 + d;
                if (sec == 0) {
                    #pragma unroll
                    for (int i = 0; i < 4; ++i) {
                        float val = acc[mi][ni][i] + bv;
                        // bake attn scale 1/8 and log2(e) for exp2-domain softmax
                        qbf[idxSD + (long)i * 64] = f2bf(val * 0.1803368801111244f);
                    }
                } else if (sec == 1) {
                    #pragma unroll
                    for (int i = 0; i < 4; ++i) {
                        float val = acc[mi][ni][i] + bv;
                        kout[idxSD + (long)i * 64] = val;
                        kbf[idxSD + (long)i * 64] = f2bf(val);
                    }
                } else {
                    #pragma unroll
                    for (int i = 0; i < 4; ++i) {
                        float val = acc[mi][ni][i] + bv;
                        vout[idxSD + (long)i * 64] = val;  // fp32 V out; vT_bf made by transpose_v
                    }
                }
            } else {
                #pragma unroll
                for (int i = 0; i < 4; ++i) {
                    int row = m0 + wm * 64 + mi * 16 + lr * 4 + i;
                    outf[(long)row * N + col] = acc[mi][ni][i] + bv;
                }
            }
        }
    }
}

// ---------------- flash attention (LDS-staged K/V, 32 q-rows/wave, static softmax) ----------------
// grid: 512 blocks = 32 bh x 16 q-tiles of 128 rows; 256 threads (4 waves x 32 q-rows).
// Each wave owns TWO q-strips: A = qt*128+wv*16, B = A+64. Every K/V fragment read from
// LDS feeds 2 MFMAs (one per strip) -> per-block-step ds_read_b128 count halves vs 16q/wave.
// Per k-step: block stages K-tile [64][64] + V^T-tile [64][64] once (global_load_lds w16,
// double-buffered, chunk XOR-swizzle both-sides). STATIC softmax (p = exp2(s'), no max:
// causal rows contain the diagonal -> row max p in [1, 2^~26], inside f32/bf16 range).
// S^T = mfma(K,Q), PV = mfma(V^T,P^T): lane owns q = lane&15; lsum per-lane partial,
// 2-shuffle reduce once in epilogue. Only each wave's FINAL step has a dead A-strip (~3% waste).
__global__ __launch_bounds__(256, 3) void attn_kernel(const short* __restrict__ qbf,
                                                      const short* __restrict__ kbf,
                                                      const short* __restrict__ vbfT,
                                                      short* __restrict__ obf) {
    const int bid = blockIdx.x;
    const int xcd = bid & 7, r = bid >> 3;      // 64 slots per XCD
    const int head_local = r & 3, q16 = r >> 2; // q16 in 0..15
    const int qt = (q16 < 8) ? (q16 + 8) : (15 - q16);  // slot r and r+32 sum to 17 units
    const int bh = xcd * 4 + head_local;
    const int tid = threadIdx.x;
    const int wv = tid >> 6, l = tid & 63;      // wv in 0..3
    const int lr = l >> 4, lc = l & 15;
    const int q0A = qt * 128 + wv * 16;
    const int q0B = q0A + 64;
    const long baseSD = (long)bh * 2048 * 64;   // q,k: [S][64]
    const long baseDS = (long)bh * 64 * 2048;   // vT:  [64][S]

    __shared__ __align__(16) short Ks[2][64 * 64];  // swizzled K tile   (8 KB x2)
    __shared__ __align__(16) short Vs[2][64 * 64];  // swizzled V^T tile (8 KB x2)
    __shared__ short P[4][2][16][76];               // per-wave, per-strip P^T staging

    // staging: wave wv stages rows wv*16..wv*16+15 of K and of V^T (2 gload_lds16 each);
    // lane l -> row base+(l>>3), phys chunk l&7 holds logical chunk (l&7)^(l>>3).
    const int sSub = l >> 3;
    const int sChunk = (l & 7) ^ sSub;
    auto stage = [&](int kt, int nb) {
        const int k0 = kt * 64;
        const int r0 = wv * 16 + sSub;
        gload_lds16(kbf + baseSD + (long)(k0 + r0) * 64 + sChunk * 8,
                    &Ks[nb][(wv * 16) * 64]);
        gload_lds16(kbf + baseSD + (long)(k0 + r0 + 8) * 64 + sChunk * 8,
                    &Ks[nb][(wv * 16 + 8) * 64]);
        gload_lds16(vbfT + baseDS + (long)r0 * 2048 + k0 + sChunk * 8,
                    &Vs[nb][(wv * 16) * 64]);
        gload_lds16(vbfT + baseDS + (long)(r0 + 8) * 2048 + k0 + sChunk * 8,
                    &Vs[nb][(wv * 16 + 8) * 64]);
    };

    // Q fragments (B-operand): lane holds col q = q0X+lc, d = lr*8.. (+32 second half)
    s16x8 qfA0 = *(const s16x8*)&qbf[baseSD + (long)(q0A + lc) * 64 + lr * 8];
    s16x8 qfA1 = *(const s16x8*)&qbf[baseSD + (long)(q0A + lc) * 64 + lr * 8 + 32];
    s16x8 qfB0 = *(const s16x8*)&qbf[baseSD + (long)(q0B + lc) * 64 + lr * 8];
    s16x8 qfB1 = *(const s16x8*)&qbf[baseSD + (long)(q0B + lc) * 64 + lr * 8 + 32];

    float lsumA = 0.f, lsumB = 0.f;    // per-lane PARTIAL sums
    f32x4 OA[4] = {}, OB[4] = {};      // O^T per strip

    const int nkt = 2 * qt + 2;        // k-tiles covering rows 0..qt*128+127
    const int sw = lc & 7;             // read-side swizzle key (row&7 == lc&7 for all frags)

    stage(0, 0);
    __syncthreads();                   // drains vmcnt -> buf0 ready
    int cur = 0;

    for (int kt = 0; kt < nkt; ++kt) {
        const int k0 = kt * 64;
        if (kt + 1 < nkt) stage(kt + 1, cur ^ 1);

        const short* Kb = Ks[cur];
        const short* Vb = Vs[cur];
        // S^T = K @ Q^T for both strips; each K fragment feeds 2 MFMAs
        f32x4 scA[4], scB[4];
        #pragma unroll
        for (int kk = 0; kk < 4; ++kk) {
            const int row = kk * 16 + lc;
            s16x8 kf0 = *(const s16x8*)&Kb[row * 64 + ((lr ^ sw) * 8)];
            s16x8 kf1 = *(const s16x8*)&Kb[row * 64 + (((lr + 4) ^ sw) * 8)];
            f32x4 zA = {}, zB = {};
            zA = __builtin_amdgcn_mfma_f32_16x16x32_bf16(kf0, qfA0, zA, 0, 0, 0);
            zA = __builtin_amdgcn_mfma_f32_16x16x32_bf16(kf1, qfA1, zA, 0, 0, 0);
            zB = __builtin_amdgcn_mfma_f32_16x16x32_bf16(kf0, qfB0, zB, 0, 0, 0);
            zB = __builtin_amdgcn_mfma_f32_16x16x32_bf16(kf1, qfB1, zB, 0, 0, 0);
            scA[kk] = zA; scB[kk] = zB;
        }
        // causal masks (k index = k0+kk*16+lr*4+i, q = q0X+lc)
        if (k0 + 63 > q0A) {
            #pragma unroll
            for (int kk = 0; kk < 4; ++kk)
                #pragma unroll
                for (int i = 0; i < 4; ++i)
                    if (k0 + kk * 16 + lr * 4 + i > q0A + lc) scA[kk][i] = -INFINITY;
        }
        if (k0 + 63 > q0B) {
            #pragma unroll
            for (int kk = 0; kk < 4; ++kk)
                #pragma unroll
                for (int i = 0; i < 4; ++i)
                    if (k0 + kk * 16 + lr * 4 + i > q0B + lc) scB[kk][i] = -INFINITY;
        }
        // STATIC softmax: p = exp2(s'); exp2(-inf) = 0 handles the mask
        #pragma unroll
        for (int kk = 0; kk < 4; ++kk) {
            s16x4 pa, pb;
            #pragma unroll
            for (int i = 0; i < 4; ++i) {
                float p = __builtin_amdgcn_exp2f(scA[kk][i]);
                lsumA += p;
                pa[i] = f2bf(p);
            }
            #pragma unroll
            for (int i = 0; i < 4; ++i) {
                float p = __builtin_amdgcn_exp2f(scB[kk][i]);
                lsumB += p;
                pb[i] = f2bf(p);
            }
            *(s16x4*)&P[wv][0][lc][kk * 16 + lr * 4] = pa;
            *(s16x4*)&P[wv][1][lc][kk * 16 + lr * 4] = pb;
        }
        // PV: O^T += V^T @ P^T; each V fragment feeds 2 MFMAs
        #pragma unroll
        for (int kk2 = 0; kk2 < 2; ++kk2) {
            s16x8 pfA, pfB;
            *(s16x4*)&pfA = *(const s16x4*)&P[wv][0][lc][kk2 * 32 + lr * 8];
            *(((s16x4*)&pfA) + 1) = *(const s16x4*)&P[wv][0][lc][kk2 * 32 + lr * 8 + 4];
            *(s16x4*)&pfB = *(const s16x4*)&P[wv][1][lc][kk2 * 32 + lr * 8];
            *(((s16x4*)&pfB) + 1) = *(const s16x4*)&P[wv][1][lc][kk2 * 32 + lr * 8 + 4];
            #pragma unroll
            for (int dt = 0; dt < 4; ++dt) {
                const int d = dt * 16 + lc;
                s16x8 vf = *(const s16x8*)&Vb[d * 64 + (((kk2 * 4 + lr) ^ sw) * 8)];
                OA[dt] = __builtin_amdgcn_mfma_f32_16x16x32_bf16(vf, pfA, OA[dt], 0, 0, 0);
                OB[dt] = __builtin_amdgcn_mfma_f32_16x16x32_bf16(vf, pfB, OB[dt], 0, 0, 0);
            }
        }
        __syncthreads();               // all done with buf[cur]; stage(kt+1) drained
        cur ^= 1;
    }

    // epilogue: reduce partial lsums across lr-group, O /= lsum; packed 8B stores
    lsumA += __shfl_xor(lsumA, 16);
    lsumA += __shfl_xor(lsumA, 32);
    lsumB += __shfl_xor(lsumB, 16);
    lsumB += __shfl_xor(lsumB, 32);
    const int b = bh >> 4, h = bh & 15;
    float invA = 1.0f / lsumA, invB = 1.0f / lsumB;
    #pragma unroll
    for (int dt = 0; dt < 4; ++dt) {
        s16x4 oa, ob;
        #pragma unroll
        for (int i = 0; i < 4; ++i) {
            oa[i] = f2bf(OA[dt][i] * invA);
            ob[i] = f2bf(OB[dt][i] * invB);
        }
        *(s16x4*)&obf[(long)(b * 2048 + q0A + lc) * 1024 + h * 64 + dt * 16 + lr * 4] = oa;
        *(s16x4*)&obf[(long)(b * 2048 + q0B + lc) * 1024 + h * 64 + dt * 16 + lr * 4] = ob;
    }
}

// ---------------- launch ----------------

extern "C" void kernel_launch(void* const* d_in, const int* in_sizes, int n_in,
                              void* d_out, int out_size, void* d_ws, size_t ws_size,
                              hipStream_t stream) {
    const float* x = (const float*)d_in[0];
    const float* qkv_w = (const float*)d_in[1];
    const float* qkv_b = (const float*)d_in[2];
    const float* proj_w = (const float*)d_in[3];
    const float* proj_b = (const float*)d_in[4];

    float* out = (float*)d_out;
    float* kout = out + 4194304;
    float* vout = out + 8388608;

    short* x_bf = (short*)d_ws;           // 4194304 shorts
    short* wT1 = x_bf + 4194304;          // 3145728
    short* wT2 = wT1 + 3145728;           // 1048576
    short* q_bf = wT2 + 1048576;          // 4194304
    short* k_bf = q_bf + 4194304;         // 4194304
    short* vT_bf = k_bf + 4194304;        // 4194304 ([B,H,D,S])
    short* o_bf = x_bf;                   // alias: x_bf dead after GEMM1

    convert_f32_bf16<<<2048, 256, 0, stream>>>(x, x_bf, 4194304);
    transpose_conv<<<dim3(96, 32), dim3(32, 8), 0, stream>>>(qkv_w, wT1, 1024, 3072);
    transpose_conv<<<dim3(32, 32), dim3(32, 8), 0, stream>>>(proj_w, wT2, 1024, 1024);

    gemm_bf16<1><<<dim3(24, 32), 256, 0, stream>>>(x_bf, wT1, qkv_b, 4096, 3072, 1024,
                                                   nullptr, q_bf, k_bf, kout, vout);

    transpose_v<<<dim3(64, 2, 32), dim3(32, 8), 0, stream>>>(vout, vT_bf);

    attn_kernel<<<512, 256, 0, stream>>>(q_bf, k_bf, vT_bf, o_bf);

    gemm_bf16<2><<<dim3(8, 32), 256, 0, stream>>>(o_bf, wT2, proj_b, 4096, 1024, 1024,
                                                  out, nullptr, nullptr, nullptr, nullptr);
}

// Round 12
// 133.084 us; speedup vs baseline: 1.0031x; 1.0031x over previous
//
#include <hip/hip_runtime.h>
#include <hip/hip_bf16.h>

// Shapes (fixed): B=2, S=2048, E=1024, H=16, D=64
// d_out: out[4194304] fp32 | k[4194304] fp32 [B,H,S,D] | v[4194304] fp32 [B,H,S,D]
// ws: x_bf | wT1 | wT2 | q_bf | k_bf | vT_bf ; o_bf aliases x_bf.

typedef __attribute__((ext_vector_type(4))) float f32x4;
typedef __attribute__((ext_vector_type(16))) float f32x16;
typedef __attribute__((ext_vector_type(8))) short s16x8;
typedef __attribute__((ext_vector_type(4))) short s16x4;

__device__ __forceinline__ short f2bf(float f) {
    union { float f; unsigned u; } x{f};
    unsigned r = x.u + 0x7fff + ((x.u >> 16) & 1);
    return (short)(r >> 16);
}

__device__ __forceinline__ void gload_lds16(const void* g, void* l) {
    __builtin_amdgcn_global_load_lds(
        (const __attribute__((address_space(1))) void*)g,
        (__attribute__((address_space(3))) void*)l, 16, 0, 0);
}

// ---------------- pre-pass kernels ----------------

__global__ __launch_bounds__(256) void convert_f32_bf16(const float* __restrict__ in,
                                                        short* __restrict__ out, int n) {
    int i = (blockIdx.x * 256 + threadIdx.x) * 8;
    if (i + 7 < n) {
        f32x4 a = *(const f32x4*)&in[i];
        f32x4 b = *(const f32x4*)&in[i + 4];
        s16x8 o;
        #pragma unroll
        for (int j = 0; j < 4; ++j) o[j] = f2bf(a[j]);
        #pragma unroll
        for (int j = 0; j < 4; ++j) o[j + 4] = f2bf(b[j]);
        *(s16x8*)&out[i] = o;
    }
}

// in: [K][N] fp32 row-major -> out: [N][K] bf16 row-major
__global__ __launch_bounds__(256) void transpose_conv(const float* __restrict__ in,
                                                      short* __restrict__ out, int K, int N) {
    __shared__ float tile[32][33];
    int tx = threadIdx.x, ty = threadIdx.y;  // 32 x 8
    int n0 = blockIdx.x * 32, k0 = blockIdx.y * 32;
    #pragma unroll
    for (int r = 0; r < 4; ++r)
        tile[ty + r * 8][tx] = in[(long)(k0 + ty + r * 8) * N + n0 + tx];
    __syncthreads();
    #pragma unroll
    for (int r = 0; r < 4; ++r)
        out[(long)(n0 + ty + r * 8) * K + k0 + tx] = f2bf(tile[tx][ty + r * 8]);
}

// vout fp32 [32][2048][64] (in d_out) -> vT_bf [32][64][2048] bf16, coalesced both sides
__global__ __launch_bounds__(256) void transpose_v(const float* __restrict__ vin,
                                                   short* __restrict__ vT) {
    __shared__ float tile[32][33];
    const int bh = blockIdx.z;
    const int s0 = blockIdx.x * 32, d0 = blockIdx.y * 32;
    const int tx = threadIdx.x, ty = threadIdx.y;  // 32 x 8
    const float* src = vin + (long)bh * 2048 * 64;
    short* dst = vT + (long)bh * 64 * 2048;
    #pragma unroll
    for (int r = 0; r < 4; ++r)
        tile[ty + r * 8][tx] = src[(long)(s0 + ty + r * 8) * 64 + d0 + tx];
    __syncthreads();
    #pragma unroll
    for (int r = 0; r < 4; ++r)
        dst[(long)(d0 + ty + r * 8) * 2048 + s0 + tx] = f2bf(tile[tx][ty + r * 8]);
}

// ---------------- GEMM (m97-style: 128x128 tile, BK=32, global_load_lds) ----------------
// A: [M][K] bf16, Bt: [N][K] bf16.  MODE 1: qkv epilogue. MODE 2: plain bias epilogue.

template <int MODE>
__global__ __launch_bounds__(256) void gemm_bf16(
    const short* __restrict__ A, const short* __restrict__ Bt,
    const float* __restrict__ bias, int M, int N, int K,
    float* __restrict__ outf,
    short* __restrict__ qbf, short* __restrict__ kbf,
    float* __restrict__ kout, float* __restrict__ vout) {
    __shared__ __align__(16) short As[128 * 32];
    __shared__ __align__(16) short Bs[128 * 32];
    const int tid = threadIdx.x;
    const int l = tid & 63, w = tid >> 6;
    const int lr = l >> 4, lc = l & 15;
    const int wm = w >> 1, wn = w & 1;
    const int m0 = blockIdx.y * 128, n0 = blockIdx.x * 128;

    f32x4 acc[4][4] = {};
    const int c0 = tid, c1 = tid + 256;  // 16B chunks; chunk c -> row c>>2, seg c&3

    for (int kb = 0; kb < K; kb += 32) {
        __syncthreads();
        gload_lds16(A + (long)(m0 + (c0 >> 2)) * K + kb + (c0 & 3) * 8, As + c0 * 8);
        gload_lds16(A + (long)(m0 + (c1 >> 2)) * K + kb + (c1 & 3) * 8, As + c1 * 8);
        gload_lds16(Bt + (long)(n0 + (c0 >> 2)) * K + kb + (c0 & 3) * 8, Bs + c0 * 8);
        gload_lds16(Bt + (long)(n0 + (c1 >> 2)) * K + kb + (c1 & 3) * 8, Bs + c1 * 8);
        __syncthreads();
        s16x8 af[4], bfr[4];
        #pragma unroll
        for (int mi = 0; mi < 4; ++mi)
            af[mi] = *(const s16x8*)&As[(wm * 64 + mi * 16 + lc) * 32 + lr * 8];
        #pragma unroll
        for (int ni = 0; ni < 4; ++ni)
            bfr[ni] = *(const s16x8*)&Bs[(wn * 64 + ni * 16 + lc) * 32 + lr * 8];
        #pragma unroll
        for (int mi = 0; mi < 4; ++mi)
            #pragma unroll
            for (int ni = 0; ni < 4; ++ni)
                acc[mi][ni] = __builtin_amdgcn_mfma_f32_16x16x32_bf16(
                    af[mi], bfr[ni], acc[mi][ni], 0, 0, 0);
    }

    #pragma unroll
    for (int mi = 0; mi < 4; ++mi) {
        #pragma unroll
        for (int ni = 0; ni < 4; ++ni) {
            int col = n0 + wn * 64 + ni * 16 + lc;
            float bv = bias[col];
            if (MODE == 1) {
                int sec = col >> 10, rem = col & 1023;
                int h = rem >> 6, d = rem & 63;
                int row0 = m0 + wm * 64 + mi * 16 + lr * 4;
                int b = row0 >> 11, s0 = row0 & 2047;
                long idxSD = ((long)((b << 4) + h) * 2048 + s0) * 64 + d;
                if (sec == 0) {
                    #pragma unroll
                    for (int i = 0; i < 4; ++i) {
                        float val = acc[mi][ni][i] + bv;
                        // bake attn scale 1/8 and log2(e) for exp2-domain softmax
                        qbf[idxSD + (long)i * 64] = f2bf(val * 0.1803368801111244f);
                    }
                } else if (sec == 1) {
                    #pragma unroll
                    for (int i = 0; i < 4; ++i) {
                        float val = acc[mi][ni][i] + bv;
                        kout[idxSD + (long)i * 64] = val;
                        kbf[idxSD + (long)i * 64] = f2bf(val);
                    }
                } else {
                    #pragma unroll
                    for (int i = 0; i < 4; ++i) {
                        float val = acc[mi][ni][i] + bv;
                        vout[idxSD + (long)i * 64] = val;  // fp32 V out; vT_bf made by transpose_v
                    }
                }
            } else {
                #pragma unroll
                for (int i = 0; i < 4; ++i) {
                    int row = m0 + wm * 64 + mi * 16 + lr * 4 + i;
                    outf[(long)row * N + col] = acc[mi][ni][i] + bv;
                }
            }
        }
    }
}

// ---------------- flash attention (32x32 MFMA, pi-permuted in-register P) ----------------
// grid: 512 blocks = 32 bh x 16 q-tiles of 128 rows; 256 threads (4 waves x 32 q-rows).
// Per 64-key step: block stages K [64k][64d] + V^T [64d][64k] into LDS once (global_load_lds
// w16, double-buffered, chunk XOR-swizzle both-sides). 32x32x16 MFMAs:
//   QK:  S^T[64k x 32q] = mfma(A=K, B=Q^T), 2 kk2 x 4 dd = 8 MFMAs.
//   PV:  O^T[64d x 32q] += mfma(A=V^T, B=P^T), 2 dt2 x 4 frag = 8 MFMAs.
// C-layout (guide-verified): col q = lane&31, row = (r&3)+8*(r>>2)+4*(lane>>5).
// P stays IN REGISTERS via kdim permutation pi: MFMA sums over kdim, so permuting kdim
// labels identically on A and B leaves the product invariant. Choose pi(h*8+j) = the k-rows
// the lane ALREADY holds in C ({0,1,2,3,8..11} for h=0; {4..7,12..15} for h=1):
//   B-fragment = f2bf-pack of the lane's own 8 p values IN ORDER (no cross-lane ops at all);
//   A-fragment (V^T) = two ds_read_b64 at k offsets fb+4h and fb+8+4h (8B-aligned).
// STATIC softmax: p = exp2(s'), no max-tracking (causal rows contain the diagonal -> row
// max p in [1, 2^~26]); lsum per-lane partial over its k-subset, merged by one shfl_xor(32).
__global__ __launch_bounds__(256, 2) void attn_kernel(const short* __restrict__ qbf,
                                                      const short* __restrict__ kbf,
                                                      const short* __restrict__ vbfT,
                                                      short* __restrict__ obf) {
    const int bid = blockIdx.x;
    const int xcd = bid & 7, r = bid >> 3;      // 64 slots per XCD
    const int head_local = r & 3, q16 = r >> 2; // q16 in 0..15
    const int qt = (q16 < 8) ? (q16 + 8) : (15 - q16);  // slot r and r+32 sum to 17 units
    const int bh = xcd * 4 + head_local;
    const int tid = threadIdx.x;
    const int wv = tid >> 6, l = tid & 63;      // wv in 0..3
    const int h = l >> 5;                        // lane half
    const int l8 = l & 7;
    const int q0 = qt * 128 + wv * 32;           // this wave's 32-q strip
    const int qlane = q0 + (l & 31);
    const long baseSD = (long)bh * 2048 * 64;   // q,k: [S][64]
    const long baseDS = (long)bh * 64 * 2048;   // vT:  [64][S]

    __shared__ __align__(16) short Ks[2][64 * 64];  // swizzled K tile   (8 KB x2)
    __shared__ __align__(16) short Vs[2][64 * 64];  // swizzled V^T tile (8 KB x2)

    // staging: wave wv stages rows wv*16..wv*16+15; lane l -> row base+(l>>3),
    // phys chunk l&7 holds logical chunk (l&7)^(l>>3)  (row&7 == l>>3).
    const int sSub = l >> 3;
    const int sChunk = (l & 7) ^ sSub;
    auto stage = [&](int kt, int nb) {
        const int k0 = kt * 64;
        const int r0 = wv * 16 + sSub;
        gload_lds16(kbf + baseSD + (long)(k0 + r0) * 64 + sChunk * 8,
                    &Ks[nb][(wv * 16) * 64]);
        gload_lds16(kbf + baseSD + (long)(k0 + r0 + 8) * 64 + sChunk * 8,
                    &Ks[nb][(wv * 16 + 8) * 64]);
        gload_lds16(vbfT + baseDS + (long)r0 * 2048 + k0 + sChunk * 8,
                    &Vs[nb][(wv * 16) * 64]);
        gload_lds16(vbfT + baseDS + (long)(r0 + 8) * 2048 + k0 + sChunk * 8,
                    &Vs[nb][(wv * 16 + 8) * 64]);
    };

    // Q fragments (B-operand, 32x32x16): lane holds col q = qlane, kdim d = dd*16 + h*8 + j
    s16x8 qf[4];
    #pragma unroll
    for (int dd = 0; dd < 4; ++dd)
        qf[dd] = *(const s16x8*)&qbf[baseSD + (long)qlane * 64 + dd * 16 + h * 8];

    float lsum = 0.f;                  // per-lane PARTIAL sum over this lane's k-subset
    f32x16 O[2] = {};                  // O^T: O[dt2][rr] = O[d = dt2*32+(rr&3)+8*(rr>>2)+4h][qlane]

    const int nkt = 2 * qt + 2;        // k-tiles covering rows 0..qt*128+127

    stage(0, 0);
    __syncthreads();                   // drains vmcnt -> buf0 ready
    int cur = 0;

    for (int kt = 0; kt < nkt; ++kt) {
        const int k0 = kt * 64;
        if (kt + 1 < nkt) stage(kt + 1, cur ^ 1);

        if (k0 <= q0 + 31) {           // strip has unmasked keys in this tile
            const short* Kb = Ks[cur];
            const short* Vb = Vs[cur];
            #pragma unroll
            for (int kk2 = 0; kk2 < 2; ++kk2) {
                // QK: S^T[32k x 32q] accumulated over d
                f32x16 z = {};
                #pragma unroll
                for (int dd = 0; dd < 4; ++dd) {
                    s16x8 kf = *(const s16x8*)&Kb[(kk2 * 32 + (l & 31)) * 64 +
                                                  (((2 * dd + h) ^ l8) * 8)];
                    z = __builtin_amdgcn_mfma_f32_32x32x16_bf16(kf, qf[dd], z, 0, 0, 0);
                }
                // causal mask: k = k0 + kk2*32 + (rr&3)+8*(rr>>2)+4h, q = qlane
                if (k0 + 63 > q0) {
                    #pragma unroll
                    for (int rr = 0; rr < 16; ++rr) {
                        int kpos = k0 + kk2 * 32 + (rr & 3) + 8 * (rr >> 2) + 4 * h;
                        if (kpos > qlane) z[rr] = -INFINITY;
                    }
                }
                // static softmax: p = exp2(s'); exp2(-inf) = 0 handles the mask
                float p[16];
                #pragma unroll
                for (int rr = 0; rr < 16; ++rr) {
                    p[rr] = __builtin_amdgcn_exp2f(z[rr]);
                    lsum += p[rr];
                }
                // PV per 16-k fragment f (k base fb = kk2*32 + f*16), pi-permuted kdim:
                //   B = pack of own p[f*8..f*8+7] (f2bf, in order);
                //   A = V^T rows, two b64 at k = fb+4h and fb+8+4h.
                #pragma unroll
                for (int f = 0; f < 2; ++f) {
                    s16x8 pf;
                    #pragma unroll
                    for (int j = 0; j < 8; ++j) pf[j] = f2bf(p[f * 8 + j]);
                    const int c0 = kk2 * 4 + f * 2;       // logical chunk of fb
                    #pragma unroll
                    for (int dt2 = 0; dt2 < 2; ++dt2) {
                        const short* vr = &Vb[(dt2 * 32 + (l & 31)) * 64];
                        s16x8 vf;
                        *(s16x4*)&vf = *(const s16x4*)&vr[(c0 ^ l8) * 8 + 4 * h];
                        *(((s16x4*)&vf) + 1) = *(const s16x4*)&vr[((c0 + 1) ^ l8) * 8 + 4 * h];
                        O[dt2] = __builtin_amdgcn_mfma_f32_32x32x16_bf16(vf, pf,
                                                                         O[dt2], 0, 0, 0);
                    }
                }
            }
        }
        __syncthreads();               // all done with buf[cur]; stage(kt+1) drained
        cur ^= 1;
    }

    // epilogue: merge lane halves' partial lsum (1 shuffle), O /= lsum; packed 8B stores
    lsum += __shfl_xor(lsum, 32);
    const int b = bh >> 4, hd = bh & 15;
    float inv = 1.0f / lsum;
    #pragma unroll
    for (int dt2 = 0; dt2 < 2; ++dt2) {
        #pragma unroll
        for (int g = 0; g < 4; ++g) {
            s16x4 o;
            #pragma unroll
            for (int i = 0; i < 4; ++i) o[i] = f2bf(O[dt2][g * 4 + i] * inv);
            const int d = dt2 * 32 + 8 * g + 4 * h;
            *(s16x4*)&obf[(long)(b * 2048 + qlane) * 1024 + hd * 64 + d] = o;
        }
    }
}

// ---------------- launch ----------------

extern "C" void kernel_launch(void* const* d_in, const int* in_sizes, int n_in,
                              void* d_out, int out_size, void* d_ws, size_t ws_size,
                              hipStream_t stream) {
    const float* x = (const float*)d_in[0];
    const float* qkv_w = (const float*)d_in[1];
    const float* qkv_b = (const float*)d_in[2];
    const float* proj_w = (const float*)d_in[3];
    const float* proj_b = (const float*)d_in[4];

    float* out = (float*)d_out;
    float* kout = out + 4194304;
    float* vout = out + 8388608;

    short* x_bf = (short*)d_ws;           // 4194304 shorts
    short* wT1 = x_bf + 4194304;          // 3145728
    short* wT2 = wT1 + 3145728;           // 1048576
    short* q_bf = wT2 + 1048576;          // 4194304
    short* k_bf = q_bf + 4194304;         // 4194304
    short* vT_bf = k_bf + 4194304;        // 4194304 ([B,H,D,S])
    short* o_bf = x_bf;                   // alias: x_bf dead after GEMM1

    convert_f32_bf16<<<2048, 256, 0, stream>>>(x, x_bf, 4194304);
    transpose_conv<<<dim3(96, 32), dim3(32, 8), 0, stream>>>(qkv_w, wT1, 1024, 3072);
    transpose_conv<<<dim3(32, 32), dim3(32, 8), 0, stream>>>(proj_w, wT2, 1024, 1024);

    gemm_bf16<1><<<dim3(24, 32), 256, 0, stream>>>(x_bf, wT1, qkv_b, 4096, 3072, 1024,
                                                   nullptr, q_bf, k_bf, kout, vout);

    transpose_v<<<dim3(64, 2, 32), dim3(32, 8), 0, stream>>>(vout, vT_bf);

    attn_kernel<<<512, 256, 0, stream>>>(q_bf, k_bf, vT_bf, o_bf);

    gemm_bf16<2><<<dim3(8, 32), 256, 0, stream>>>(o_bf, wT2, proj_b, 4096, 1024, 1024,
                                                  out, nullptr, nullptr, nullptr, nullptr);
}